// Round 9
// baseline (137.328 us; speedup 1.0000x reference)
//
#include <hip/hip_runtime.h>
#include <math.h>

#define NM   6400
#define DT   64          // samples per chunk == lanes per wave
#define NC   352         // padded chunk count (345 real, 352 = 4*88)
#define CB   16          // chunks per block (4 waves x 4 chunks)
#define MB   64          // modes per block tile (32KB LDS)
#define MGY  100         // NM / MB

static __device__ __forceinline__ float softplusf(float x) {
    return log1pf(expf(-fabsf(x))) + fmaxf(x, 0.0f);
}
static __device__ __forceinline__ float sigmoidf(float x) {
    return 1.0f / (1.0f + expf(-x));
}

// ONE launch, 6400 threads (one per mode):
//  - per-mode fp32 constants (identical numerics to previous rounds)
//  - cdsd[m][dt] = (Re,Im) of r^dt, dt=0..63, generated in double, 3.3MB
//  - statePair[c>>1][m] = float4{S_even,C_even,S_odd,C_odd}: z(64c) chunk
//    states via z *= R64 (double), 4 interleaved chains of 88 chunks
//  - stride-zero of out[] (atomics target)
__global__ void setup_gen_kernel(const float* __restrict__ mu_raw,
                                 const float* __restrict__ Dmu_raw,
                                 const float* __restrict__ T0mu_raw,
                                 const float* __restrict__ Ly_raw,
                                 const float* __restrict__ xo_raw,
                                 const float* __restrict__ yo_raw,
                                 float2* __restrict__ cdsd,
                                 float4* __restrict__ statePair,
                                 float* __restrict__ out, int T)
{
    int id = blockIdx.x * blockDim.x + threadIdx.x;
    int gsz = gridDim.x * blockDim.x;
    for (int i = id; i < T; i += gsz) out[i] = 0.0f;
    if (id >= NM) return;

    const float KF   = 1.0f / 44100.0f;
    const float PI_F = (float)M_PI;
    const double om2sq = (2.0 * M_PI * 500.0) * (2.0 * M_PI * 500.0);
    const float ALPHA_F  = (float)(3.0 * M_LN10 / om2sq * (om2sq / 6.0));
    const float BETA_F   = (float)(3.0 * M_LN10 / om2sq * (1.0 - 1.0 / 6.0));
    const float MAX_OM_F = (float)(10000.0 * 2.0 * M_PI);
    const float MIN_OM_F = (float)(20.0 * 2.0 * M_PI);
    const float KK_F     = (float)((1.0 / 44100.0) * (1.0 / 44100.0));
    const double Kd      = 1.0 / 44100.0;

    float mu   = (softplusf(mu_raw[0])   + 1e-4f) * 2.43f;
    float Dmu  = (softplusf(Dmu_raw[0])  + 1e-4f) * 0.002452f;
    float T0mu = (softplusf(T0mu_raw[0]) + 1e-4f) * 0.004115f;
    float Ly   = 1.1f + 2.9f * sigmoidf(Ly_raw[0]);
    float xo   = 0.245f + 0.255f * sigmoidf(xo_raw[0]);
    float yo   = __fadd_rn(__fmul_rn(0.51f, Ly),
                           __fmul_rn(__fmul_rn(0.49f, Ly), sigmoidf(yo_raw[0])));

    float mf = (float)(id / 80 + 1);
    float nf = (float)(id % 80 + 1);

    float am = __fmul_rn(__fmul_rn(mf, PI_F), 2.0f);
    float bn = __fdiv_rn(__fmul_rn(nf, PI_F), Ly);
    float g1 = __fadd_rn(__fmul_rn(am, am), __fmul_rn(bn, bn));
    float omega_sq = __fadd_rn(__fmul_rn(T0mu, g1),
                               __fmul_rn(__fmul_rn(Dmu, g1), g1));
    float omega = sqrtf(fmaxf(omega_sq, 0.0f));
    float valid = (omega <= MAX_OM_F && omega >= MIN_OM_F) ? 1.0f : 0.0f;

    float xi_pi = (float)(0.05 * M_PI);
    float yi = __fmul_rn(0.1f, Ly);
    float InW = __fmul_rn(
        cosf(__fmul_rn(__fmul_rn(xi_pi, mf), 2.0f)),
        cosf(__fdiv_rn(__fmul_rn(__fmul_rn(yi, PI_F), nf), Ly)));
    float OutW = __fmul_rn(
        cosf(__fmul_rn(__fmul_rn(__fmul_rn(xo, PI_F), mf), 2.0f)),
        cosf(__fdiv_rn(__fmul_rn(__fmul_rn(yo, PI_F), nf), Ly)));

    float sigma = __fadd_rn(ALPHA_F, __fmul_rn(BETA_F, __fmul_rn(omega, omega)));
    float ms = __fmul_rn(__fmul_rn(__fmul_rn(0.25f, mu), 0.5f), Ly);
    float P = __fmul_rn(
        __fdiv_rn(__fmul_rn(__fmul_rn(__fmul_rn(OutW, InW), KK_F),
                            expf(__fmul_rn(-sigma, KF))),
                  ms),
        valid);
    float den = __fadd_rn(sinf(__fmul_rn(omega, KF)), 1e-8f);
    float A = __fdiv_rn(P, den);

    // ---- double-precision phasor machinery ----
    double th = (double)omega * Kd;
    double dd = exp(-(double)sigma * Kd);
    double rre = dd * cos(th), rim = dd * sin(th);   // r = e^{(-sigma+i*omega)K}

    // cdsd[m][dt] = r^dt, dt = 0..63 (cur ends as R64 = r^64)
    double cre = 1.0, cim = 0.0;
    float2* cd = cdsd + (size_t)id * DT;
    #pragma unroll 4
    for (int dt = 0; dt < DT; ++dt) {
        cd[dt] = make_float2((float)cre, (float)cim);
        double nre = cre * rre - cim * rim;
        double nim = cre * rim + cim * rre;
        cre = nre; cim = nim;
    }
    double R64re = cre, R64im = cim;

    // R88 = R64^88 = R64^64 * R64^16 * R64^8 via squaring ladder
    double q_re = R64re, q_im = R64im;               // R64^1
    double p8re = 0, p8im = 0, p16re = 0, p16im = 0, p64re = 0, p64im = 0;
    #pragma unroll
    for (int s = 1; s <= 6; ++s) {                   // squarings: ^2,^4,^8,^16,^32,^64
        double nre = q_re * q_re - q_im * q_im;
        double nim = 2.0 * q_re * q_im;
        q_re = nre; q_im = nim;
        if (s == 3) { p8re = q_re;  p8im = q_im; }
        if (s == 4) { p16re = q_re; p16im = q_im; }
        if (s == 6) { p64re = q_re; p64im = q_im; }
    }
    double t1re = p64re * p16re - p64im * p16im;
    double t1im = p64re * p16im + p64im * p16re;
    double R88re = t1re * p8re - t1im * p8im;
    double R88im = t1re * p8im + t1im * p8re;

    // z(0) = A * e^{+sigma*K} (value at t=0 is Im(z)=0)
    double z0re = (double)A * exp((double)sigma * Kd), z0im = 0.0;
    // 4 interleaved chains: chunks j, 88+j, 176+j, 264+j
    double zr[4], zi[4];
    zr[0] = z0re; zi[0] = z0im;
    #pragma unroll
    for (int k = 1; k < 4; ++k) {
        zr[k] = zr[k-1] * R88re - zi[k-1] * R88im;
        zi[k] = zr[k-1] * R88im + zi[k-1] * R88re;
    }

    float evS[4], evC[4];
    #pragma unroll 1
    for (int j = 0; j < 88; ++j) {
        if ((j & 1) == 0) {
            #pragma unroll
            for (int k = 0; k < 4; ++k) { evS[k] = (float)zi[k]; evC[k] = (float)zr[k]; }
        } else {
            #pragma unroll
            for (int k = 0; k < 4; ++k) {
                int c = k * 88 + j;                  // odd chunk
                statePair[(size_t)(c >> 1) * NM + id] =
                    make_float4(evS[k], evC[k], (float)zi[k], (float)zr[k]);
            }
        }
        #pragma unroll
        for (int k = 0; k < 4; ++k) {                // advance one chunk: z *= R64
            double nre = zr[k] * R64re - zi[k] * R64im;
            double nim = zr[k] * R64im + zi[k] * R64re;
            zr[k] = nre; zi[k] = nim;
        }
    }
}

// out[64c+dt] = sum_m S_m(c)*Re(r_m^dt) + C_m(c)*Im(r_m^dt)
// Block: 64-mode x 64-dt cdsd tile in LDS (32KB), 4 waves x 4 chunks each,
// lane = dt. Per mode: 2 broadcast dwordx4 state loads + 1 ds_read_b64 +
// 8 FMAs covering 256 mode-samples. One atomicAdd per lane per chunk at end.
__global__ __launch_bounds__(256) void gemm_kernel(
    const float2* __restrict__ cdsd,
    const float4* __restrict__ statePair,
    float* __restrict__ out, int T)
{
    __shared__ float2 tile[MB * DT];                 // 32 KB
    const int tid = threadIdx.x;
    const int mBase = blockIdx.y * MB;

    // stage cdsd tile (linear copy, coalesced float4)
    const float4* src = (const float4*)(cdsd + (size_t)mBase * DT);
    float4* dst = (float4*)tile;
    #pragma unroll
    for (int i = 0; i < (MB * DT / 2) / 256; ++i)
        dst[i * 256 + tid] = src[i * 256 + tid];
    __syncthreads();

    const int wave = tid >> 6, lane = tid & 63;
    const int c0 = blockIdx.x * CB + wave * 4;       // even
    const float4* sp0 = statePair + (size_t)(c0 >> 1) * NM + mBase;
    const float4* sp1 = sp0 + NM;                    // next pair (c0+2, c0+3)

    float acc0 = 0.0f, acc1 = 0.0f, acc2 = 0.0f, acc3 = 0.0f;
    #pragma unroll 4
    for (int m = 0; m < MB; ++m) {
        float2 w = tile[m * DT + lane];              // (Re, Im) of r^lane
        float4 sA = sp0[m];                          // S_c0, C_c0, S_c0+1, C_c0+1
        float4 sB = sp1[m];                          // S_c0+2, C_c0+2, ...
        acc0 = __fmaf_rn(sA.x, w.x, acc0); acc0 = __fmaf_rn(sA.y, w.y, acc0);
        acc1 = __fmaf_rn(sA.z, w.x, acc1); acc1 = __fmaf_rn(sA.w, w.y, acc1);
        acc2 = __fmaf_rn(sB.x, w.x, acc2); acc2 = __fmaf_rn(sB.y, w.y, acc2);
        acc3 = __fmaf_rn(sB.z, w.x, acc3); acc3 = __fmaf_rn(sB.w, w.y, acc3);
    }

    int t = c0 * DT + lane;
    if (t          < T) atomicAdd(&out[t],          acc0);
    if (t +     DT < T) atomicAdd(&out[t +     DT], acc1);
    if (t + 2 * DT < T) atomicAdd(&out[t + 2 * DT], acc2);
    if (t + 3 * DT < T) atomicAdd(&out[t + 3 * DT], acc3);
}

// Single block: find peak |out|, then divide through.
__global__ __launch_bounds__(1024) void norm_kernel(float* __restrict__ out, int T)
{
    __shared__ float red[16];
    __shared__ float peakv;
    float mx = 0.0f;
    for (int i = threadIdx.x; i < T; i += 1024) mx = fmaxf(mx, fabsf(out[i]));
    #pragma unroll
    for (int off = 32; off > 0; off >>= 1)
        mx = fmaxf(mx, __shfl_xor(mx, off, 64));
    int lane = threadIdx.x & 63, wv = threadIdx.x >> 6;
    if (lane == 0) red[wv] = mx;
    __syncthreads();
    if (threadIdx.x == 0) {
        float m = red[0];
        #pragma unroll
        for (int i = 1; i < 16; ++i) m = fmaxf(m, red[i]);
        peakv = m + 1e-8f;
    }
    __syncthreads();
    float pk = peakv;
    for (int i = threadIdx.x; i < T; i += 1024) out[i] = __fdiv_rn(out[i], pk);
}

extern "C" void kernel_launch(void* const* d_in, const int* in_sizes, int n_in,
                              void* d_out, int out_size, void* d_ws, size_t ws_size,
                              hipStream_t stream)
{
    const float* mu   = (const float*)d_in[0];
    const float* Dmu  = (const float*)d_in[1];
    const float* T0mu = (const float*)d_in[2];
    const float* Lyr  = (const float*)d_in[3];
    const float* xor_ = (const float*)d_in[4];
    const float* yor_ = (const float*)d_in[5];
    float* out = (float*)d_out;

    float2* cdsd      = (float2*)d_ws;                       // 6400*64 float2 = 3.3MB
    float4* statePair = (float4*)(cdsd + (size_t)NM * DT);   // 176*6400 float4 = 18MB

    int T = out_size;

    setup_gen_kernel<<<(NM + 255) / 256, 256, 0, stream>>>(
        mu, Dmu, T0mu, Lyr, xor_, yor_, cdsd, statePair, out, T);
    gemm_kernel<<<dim3(NC / CB, MGY), 256, 0, stream>>>(cdsd, statePair, out, T);
    norm_kernel<<<1, 1024, 0, stream>>>(out, T);
}